// Round 1
// baseline (171.131 us; speedup 1.0000x reference)
//
#include <hip/hip_runtime.h>

#define D256 256
#define KT 8
#define S_SEQ 1024
#define OUTSEQ 512

// ---------------- prep: transpose/pack tables ----------------
// MW[j][o]   = {M[o][j], res_W[o][j]}                  (coalesced phase-A loads)
// PIt4[j][i] = {P[i][j], 1/p, 2*cos(2pi/p), 0}, p = i*256+j+2
__global__ __launch_bounds__(256) void k_prep(const float* __restrict__ M,
                                              const float* __restrict__ resW,
                                              const float* __restrict__ P,
                                              float2* __restrict__ MW,
                                              float4* __restrict__ PIt4) {
  const int j = blockIdx.x;
  const int t = threadIdx.x;
  MW[j * D256 + t] = make_float2(M[t * D256 + j], resW[t * D256 + j]);
  const float p = (float)(t * D256 + j + 2);
  const float ip = 1.0f / p;                       // exact-ish reciprocal (precise div)
  const float cb2 = 2.0f * __builtin_amdgcn_cosf(ip);  // v_cos takes revolutions; ip<=0.5
  PIt4[j * D256 + t] = make_float4(P[t * D256 + j], ip, cb2, 0.0f);
}

// ---------------- fused A+B: GEMM -> LN -> cos-einsum ----------------
// block = one k-tile of KT=8 rows, 256 threads (t = output dim / i)
__global__ __launch_bounds__(256) void k_AB(const float* __restrict__ x,
                                            const float2* __restrict__ MW,
                                            const float4* __restrict__ PIt4,
                                            const float* __restrict__ gamma,
                                            const float* __restrict__ beta,
                                            float* __restrict__ T,
                                            float* __restrict__ rfeat) {
  __shared__ float xs[D256][KT];   // transposed tile: xs[col][row], rows 32B -> b128 reads
  __shared__ float mu_s[KT], rs_s[KT];
  const int t = threadIdx.x;
  const int k0 = blockIdx.x * KT;

  // stage x tile (transposed)
  #pragma unroll
  for (int kk = 0; kk < KT; ++kk) xs[t][kk] = x[(k0 + kk) * D256 + t];
  __syncthreads();

  // phase A: two GEMMs sharing x
  float accM[KT] = {};
  float accR[KT] = {};
  for (int j = 0; j < D256; ++j) {
    float2 mw = MW[j * D256 + t];
    float xv[KT];
    #pragma unroll
    for (int kk = 0; kk < KT; ++kk) xv[kk] = xs[j][kk];   // broadcast LDS reads
    #pragma unroll
    for (int kk = 0; kk < KT; ++kk) {
      accM[kk] = fmaf(xv[kk], mw.x, accM[kk]);
      accR[kk] = fmaf(xv[kk], mw.y, accR[kk]);
    }
  }
  #pragma unroll
  for (int kk = 0; kk < KT; ++kk) rfeat[(k0 + kk) * D256 + t] = accR[kk];

  // LN: stash pre-LN Z in LDS (overwrite xs), reduce per row
  __syncthreads();
  #pragma unroll
  for (int kk = 0; kk < KT; ++kk) xs[t][kk] = accM[kk];
  __syncthreads();

  const int wave = t >> 6, lane = t & 63;
  for (int kk = wave; kk < KT; kk += 4) {
    float s = 0.f, sq = 0.f;
    #pragma unroll
    for (int l = 0; l < 4; ++l) {
      float v = xs[lane + 64 * l][kk];
      s += v;
      sq = fmaf(v, v, sq);
    }
    #pragma unroll
    for (int off = 32; off; off >>= 1) {
      s += __shfl_down(s, off);
      sq += __shfl_down(sq, off);
    }
    if (lane == 0) {
      float m = s * (1.0f / 256.0f);
      float var = sq * (1.0f / 256.0f) - m * m;
      mu_s[kk] = m;
      rs_s[kk] = rsqrtf(var + 1e-5f);
    }
  }
  __syncthreads();
  {
    const float g = gamma[t], be = beta[t];
    #pragma unroll
    for (int kk = 0; kk < KT; ++kk)
      xs[t][kk] = (xs[t][kk] - mu_s[kk]) * rs_s[kk] * g + be;
  }
  __syncthreads();

  // phase B: T[k,i] = sum_j Z[k,j]*P[i,j]*cos(2pi*k/p_ij)
  // Chebyshev over the k-tile: c_{m+1} = cb2*c_m - c_{m-1}
  float accT[KT] = {};
  const float kf0 = (float)k0, kf1 = (float)(k0 + 1);
  for (int j = 0; j < D256; ++j) {
    float4 pi = PIt4[j * D256 + t];
    float zv[KT];
    #pragma unroll
    for (int kk = 0; kk < KT; ++kk) zv[kk] = xs[j][kk];   // broadcast
    float r0 = kf0 * pi.y; r0 -= floorf(r0);
    float r1 = kf1 * pi.y; r1 -= floorf(r1);
    float c0 = __builtin_amdgcn_cosf(r0);    // cos(2pi * r0), r0 in [0,1)
    float c1 = __builtin_amdgcn_cosf(r1);
    accT[0] = fmaf(zv[0] * pi.x, c0, accT[0]);
    accT[1] = fmaf(zv[1] * pi.x, c1, accT[1]);
    #pragma unroll
    for (int kk = 2; kk < KT; ++kk) {
      float c2 = fmaf(pi.z, c1, -c0);
      accT[kk] = fmaf(zv[kk] * pi.x, c2, accT[kk]);
      c0 = c1;
      c1 = c2;
    }
  }
  #pragma unroll
  for (int kk = 0; kk < KT; ++kk) T[(k0 + kk) * D256 + t] = accT[kk];
}

// ---------------- stage C: out = L^T @ T + rL^T @ rfeat ----------------
// 256 blocks = b(2) x t-tile(64 of 8) x d-half(2); 256 thr = s-group(2) x d(128)
__global__ __launch_bounds__(256) void k_C(const float* __restrict__ T,
                                           const float* __restrict__ rfeat,
                                           const float* __restrict__ Linker,
                                           const float* __restrict__ rLinker,
                                           float* __restrict__ out) {
  __shared__ float red[8][128];
  const int bid = blockIdx.x;
  const int b = bid >> 7;
  const int rr = bid & 127;
  const int t0 = (rr >> 1) * 8;
  const int d0 = (rr & 1) * 128;
  const int sg = threadIdx.x >> 7;
  const int dloc = threadIdx.x & 127;
  const int d = d0 + dloc;

  float acc[8] = {};
  for (int s = sg * 512; s < sg * 512 + 512; ++s) {
    const float tv = T[(b * S_SEQ + s) * D256 + d];
    const float rv = rfeat[(b * S_SEQ + s) * D256 + d];
    #pragma unroll
    for (int u = 0; u < 8; ++u) {
      acc[u] = fmaf(tv, Linker[s * OUTSEQ + t0 + u], acc[u]);   // wave-uniform -> s_load
      acc[u] = fmaf(rv, rLinker[s * OUTSEQ + t0 + u], acc[u]);
    }
  }
  if (sg == 1) {
    #pragma unroll
    for (int u = 0; u < 8; ++u) red[u][dloc] = acc[u];
  }
  __syncthreads();
  if (sg == 0) {
    #pragma unroll
    for (int u = 0; u < 8; ++u)
      out[(b * OUTSEQ + t0 + u) * D256 + d] = acc[u] + red[u][dloc];
  }
}

extern "C" void kernel_launch(void* const* d_in, const int* in_sizes, int n_in,
                              void* d_out, int out_size, void* d_ws, size_t ws_size,
                              hipStream_t stream) {
  const float* x       = (const float*)d_in[0];
  const float* M       = (const float*)d_in[1];
  const float* P       = (const float*)d_in[2];
  const float* Linker  = (const float*)d_in[3];
  const float* gamma   = (const float*)d_in[4];
  const float* beta    = (const float*)d_in[5];
  const float* resW    = (const float*)d_in[6];
  const float* rLinker = (const float*)d_in[7];
  float* out = (float*)d_out;

  char* ws = (char*)d_ws;
  float2* MW    = (float2*)(ws);                                   // 512 KB
  float4* PIt4  = (float4*)(ws + 512 * 1024);                      // 1 MB
  float*  T     = (float*)(ws + 512 * 1024 + 1024 * 1024);         // 2 MB
  float*  rfeat = (float*)(ws + 512 * 1024 + 3 * 1024 * 1024);     // 2 MB

  hipLaunchKernelGGL(k_prep, dim3(256), dim3(256), 0, stream, M, resW, P, MW, PIt4);
  hipLaunchKernelGGL(k_AB,   dim3(256), dim3(256), 0, stream, x, MW, PIt4, gamma, beta, T, rfeat);
  hipLaunchKernelGGL(k_C,    dim3(256), dim3(256), 0, stream, T, rfeat, Linker, rLinker, out);
}

// Round 2
// 91.901 us; speedup vs baseline: 1.8621x; 1.8621x over previous
//
#include <hip/hip_runtime.h>

#define D256 256
#define KT 8
#define S_SEQ 1024
#define OUTSEQ 512

// ---------------- prep: transpose/pack tables ----------------
// MW[j][o]   = {M[o][j], res_W[o][j]}                  (coalesced phase-A loads)
// PIt4[j][i] = {P[i][j], 1/p, 2*cos(2pi/p), 0}, p = i*256+j+2
__global__ __launch_bounds__(256) void k_prep(const float* __restrict__ M,
                                              const float* __restrict__ resW,
                                              const float* __restrict__ P,
                                              float2* __restrict__ MW,
                                              float4* __restrict__ PIt4) {
  const int j = blockIdx.x;
  const int t = threadIdx.x;
  MW[j * D256 + t] = make_float2(M[t * D256 + j], resW[t * D256 + j]);
  const float p = (float)(t * D256 + j + 2);
  const float ip = 1.0f / p;                       // precise div
  const float cb2 = 2.0f * __builtin_amdgcn_cosf(ip);  // v_cos takes revolutions; ip<=0.5
  PIt4[j * D256 + t] = make_float4(P[t * D256 + j], ip, cb2, 0.0f);
}

// ---------------- fused A+B: GEMM -> LN -> cos-einsum ----------------
// block = one k-tile of KT=8 rows, 256 threads (t = output dim / i)
__global__ __launch_bounds__(256) void k_AB(const float* __restrict__ x,
                                            const float2* __restrict__ MW,
                                            const float4* __restrict__ PIt4,
                                            const float* __restrict__ gamma,
                                            const float* __restrict__ beta,
                                            float* __restrict__ T,
                                            float* __restrict__ rfeat) {
  __shared__ float xs[D256][KT];   // transposed tile: xs[col][row]
  __shared__ float mu_s[KT], rs_s[KT];
  const int t = threadIdx.x;
  const int k0 = blockIdx.x * KT;

  // stage x tile (transposed)
  #pragma unroll
  for (int kk = 0; kk < KT; ++kk) xs[t][kk] = x[(k0 + kk) * D256 + t];
  __syncthreads();

  // phase A: two GEMMs sharing x
  float accM[KT] = {};
  float accR[KT] = {};
  for (int j = 0; j < D256; ++j) {
    float2 mw = MW[j * D256 + t];
    float xv[KT];
    #pragma unroll
    for (int kk = 0; kk < KT; ++kk) xv[kk] = xs[j][kk];   // broadcast LDS reads
    #pragma unroll
    for (int kk = 0; kk < KT; ++kk) {
      accM[kk] = fmaf(xv[kk], mw.x, accM[kk]);
      accR[kk] = fmaf(xv[kk], mw.y, accR[kk]);
    }
  }
  #pragma unroll
  for (int kk = 0; kk < KT; ++kk) rfeat[(k0 + kk) * D256 + t] = accR[kk];

  // LN: stash pre-LN Z in LDS (overwrite xs), reduce per row
  __syncthreads();
  #pragma unroll
  for (int kk = 0; kk < KT; ++kk) xs[t][kk] = accM[kk];
  __syncthreads();

  const int wave = t >> 6, lane = t & 63;
  for (int kk = wave; kk < KT; kk += 4) {
    float s = 0.f, sq = 0.f;
    #pragma unroll
    for (int l = 0; l < 4; ++l) {
      float v = xs[lane + 64 * l][kk];
      s += v;
      sq = fmaf(v, v, sq);
    }
    #pragma unroll
    for (int off = 32; off; off >>= 1) {
      s += __shfl_down(s, off);
      sq += __shfl_down(sq, off);
    }
    if (lane == 0) {
      float m = s * (1.0f / 256.0f);
      float var = sq * (1.0f / 256.0f) - m * m;
      mu_s[kk] = m;
      rs_s[kk] = rsqrtf(var + 1e-5f);
    }
  }
  __syncthreads();
  {
    const float g = gamma[t], be = beta[t];
    #pragma unroll
    for (int kk = 0; kk < KT; ++kk)
      xs[t][kk] = (xs[t][kk] - mu_s[kk]) * rs_s[kk] * g + be;
  }
  __syncthreads();

  // phase B: T[k,i] = sum_j Z[k,j]*P[i,j]*cos(2pi*k/p_ij)
  // Chebyshev over the k-tile: c_{m+1} = cb2*c_m - c_{m-1}
  float accT[KT] = {};
  const float kf0 = (float)k0, kf1 = (float)(k0 + 1);
  for (int j = 0; j < D256; ++j) {
    float4 pi = PIt4[j * D256 + t];
    float zv[KT];
    #pragma unroll
    for (int kk = 0; kk < KT; ++kk) zv[kk] = xs[j][kk];   // broadcast
    float r0 = kf0 * pi.y; r0 -= floorf(r0);
    float r1 = kf1 * pi.y; r1 -= floorf(r1);
    float c0 = __builtin_amdgcn_cosf(r0);    // cos(2pi * r0)
    float c1 = __builtin_amdgcn_cosf(r1);
    accT[0] = fmaf(zv[0] * pi.x, c0, accT[0]);
    accT[1] = fmaf(zv[1] * pi.x, c1, accT[1]);
    #pragma unroll
    for (int kk = 2; kk < KT; ++kk) {
      float c2 = fmaf(pi.z, c1, -c0);
      accT[kk] = fmaf(zv[kk] * pi.x, c2, accT[kk]);
      c0 = c1;
      c1 = c2;
    }
  }
  #pragma unroll
  for (int kk = 0; kk < KT; ++kk) T[(k0 + kk) * D256 + t] = accT[kk];
}

// ---------------- stage C1: split-s partial GEMM ----------------
// grid = b(2) x t-tile(64) x s-chunk(8) = 1024 blocks; 256 thr = d
// part[sc][row][d] with row = b*512 + t0 + u
__global__ __launch_bounds__(256) void k_C1(const float* __restrict__ T,
                                            const float* __restrict__ rfeat,
                                            const float* __restrict__ Linker,
                                            const float* __restrict__ rLinker,
                                            float* __restrict__ part) {
  __shared__ float Ls[128][8];
  __shared__ float rLs[128][8];
  const int bid = blockIdx.x;
  const int sc = bid & 7;
  const int tt = (bid >> 3) & 63;
  const int b  = bid >> 9;
  const int t0 = tt * 8;
  const int s0 = sc * 128;
  const int d  = threadIdx.x;

  // stage Linker chunks (128 rows x 8 cols) via float4
  {
    const int row = threadIdx.x >> 1;
    const int c4  = (threadIdx.x & 1) * 4;
    const float4 lv = *(const float4*)&Linker[(s0 + row) * OUTSEQ + t0 + c4];
    const float4 rv = *(const float4*)&rLinker[(s0 + row) * OUTSEQ + t0 + c4];
    *(float4*)&Ls[row][c4]  = lv;
    *(float4*)&rLs[row][c4] = rv;
  }
  __syncthreads();

  float acc[8] = {};
  const float* Tp = &T[(b * S_SEQ + s0) * D256 + d];
  const float* Rp = &rfeat[(b * S_SEQ + s0) * D256 + d];
  #pragma unroll 4
  for (int s = 0; s < 128; ++s) {
    const float tv = Tp[s * D256];
    const float rv = Rp[s * D256];
    const float4 l0 = *(const float4*)&Ls[s][0];   // broadcast, conflict-free
    const float4 l1 = *(const float4*)&Ls[s][4];
    const float4 r0 = *(const float4*)&rLs[s][0];
    const float4 r1 = *(const float4*)&rLs[s][4];
    acc[0] = fmaf(tv, l0.x, acc[0]); acc[0] = fmaf(rv, r0.x, acc[0]);
    acc[1] = fmaf(tv, l0.y, acc[1]); acc[1] = fmaf(rv, r0.y, acc[1]);
    acc[2] = fmaf(tv, l0.z, acc[2]); acc[2] = fmaf(rv, r0.z, acc[2]);
    acc[3] = fmaf(tv, l0.w, acc[3]); acc[3] = fmaf(rv, r0.w, acc[3]);
    acc[4] = fmaf(tv, l1.x, acc[4]); acc[4] = fmaf(rv, r1.x, acc[4]);
    acc[5] = fmaf(tv, l1.y, acc[5]); acc[5] = fmaf(rv, r1.y, acc[5]);
    acc[6] = fmaf(tv, l1.z, acc[6]); acc[6] = fmaf(rv, r1.z, acc[6]);
    acc[7] = fmaf(tv, l1.w, acc[7]); acc[7] = fmaf(rv, r1.w, acc[7]);
  }

  const int rowbase = b * 512 + t0;
  #pragma unroll
  for (int u = 0; u < 8; ++u)
    part[(((sc << 10) + rowbase + u) << 8) + d] = acc[u];
}

// ---------------- stage C2: reduce the 8 s-chunk partials ----------------
__global__ __launch_bounds__(256) void k_C2(const float* __restrict__ part,
                                            float* __restrict__ out) {
  const int row = blockIdx.x;   // 0..1023
  const int d   = threadIdx.x;
  float s = 0.f;
  #pragma unroll
  for (int sc = 0; sc < 8; ++sc)
    s += part[(((sc << 10) + row) << 8) + d];
  out[(row << 8) + d] = s;
}

extern "C" void kernel_launch(void* const* d_in, const int* in_sizes, int n_in,
                              void* d_out, int out_size, void* d_ws, size_t ws_size,
                              hipStream_t stream) {
  const float* x       = (const float*)d_in[0];
  const float* M       = (const float*)d_in[1];
  const float* P       = (const float*)d_in[2];
  const float* Linker  = (const float*)d_in[3];
  const float* gamma   = (const float*)d_in[4];
  const float* beta    = (const float*)d_in[5];
  const float* resW    = (const float*)d_in[6];
  const float* rLinker = (const float*)d_in[7];
  float* out = (float*)d_out;

  char* ws = (char*)d_ws;
  float2* MW    = (float2*)(ws);                                   // 0.5 MB
  float4* PIt4  = (float4*)(ws + 512 * 1024);                      // 1 MB
  float*  T     = (float*)(ws + 1536 * 1024);                      // 2 MB
  float*  rfeat = (float*)(ws + 3584 * 1024);                      // 2 MB
  float*  part  = (float*)(ws + 5632 * 1024);                      // 8 MB

  hipLaunchKernelGGL(k_prep, dim3(256),  dim3(256), 0, stream, M, resW, P, MW, PIt4);
  hipLaunchKernelGGL(k_AB,   dim3(256),  dim3(256), 0, stream, x, MW, PIt4, gamma, beta, T, rfeat);
  hipLaunchKernelGGL(k_C1,   dim3(1024), dim3(256), 0, stream, T, rfeat, Linker, rLinker, part);
  hipLaunchKernelGGL(k_C2,   dim3(1024), dim3(256), 0, stream, part, out);
}

// Round 3
// 71.407 us; speedup vs baseline: 2.3966x; 1.2870x over previous
//
#include <hip/hip_runtime.h>

#define D256 256
#define KT 8
#define S_SEQ 1024
#define OUTSEQ 512

// ---------------- prep: transpose/pack tables ----------------
// MW[j][o]   = {M[o][j], res_W[o][j]}
// PIt4[j][i] = {P[i][j], 1/p, 2*cos(2pi/p), 0}, p = i*256+j+2
__global__ __launch_bounds__(256) void k_prep(const float* __restrict__ M,
                                              const float* __restrict__ resW,
                                              const float* __restrict__ P,
                                              float2* __restrict__ MW,
                                              float4* __restrict__ PIt4) {
  const int j = blockIdx.x;
  const int t = threadIdx.x;
  MW[j * D256 + t] = make_float2(M[t * D256 + j], resW[t * D256 + j]);
  const float p = (float)(t * D256 + j + 2);
  const float ip = 1.0f / p;                           // precise div
  const float cb2 = 2.0f * __builtin_amdgcn_cosf(ip);  // v_cos takes revolutions
  PIt4[j * D256 + t] = make_float4(P[t * D256 + j], ip, cb2, 0.0f);
}

// ---------------- k_A: x@M^T -> LN -> Z ; x@resW^T -> rfeat ----------------
// KT=4 rows/block, grid 512 (2 blocks/CU), 256 threads = output col
__global__ __launch_bounds__(256) void k_A(const float* __restrict__ x,
                                           const float2* __restrict__ MW,
                                           const float* __restrict__ gamma,
                                           const float* __restrict__ beta,
                                           float* __restrict__ Z,
                                           float* __restrict__ rfeat) {
  __shared__ float Zs[4][D256];    // row-major per k-row: writes & reduce conflict-free
  __shared__ float mu_s[4], rs_s[4];
  const int t = threadIdx.x;
  const int k0 = blockIdx.x * 4;

  #pragma unroll
  for (int kk = 0; kk < 4; ++kk) Zs[kk][t] = x[(k0 + kk) * D256 + t];
  __syncthreads();

  float accM[4] = {}, accR[4] = {};
  for (int j = 0; j < D256; ++j) {
    const float2 mw = MW[j * D256 + t];
    #pragma unroll
    for (int kk = 0; kk < 4; ++kk) {
      const float xv = Zs[kk][j];            // wave-broadcast
      accM[kk] = fmaf(xv, mw.x, accM[kk]);
      accR[kk] = fmaf(xv, mw.y, accR[kk]);
    }
  }
  #pragma unroll
  for (int kk = 0; kk < 4; ++kk) rfeat[(k0 + kk) * D256 + t] = accR[kk];

  __syncthreads();
  #pragma unroll
  for (int kk = 0; kk < 4; ++kk) Zs[kk][t] = accM[kk];
  __syncthreads();

  // LN reduce: wave w reduces row w
  const int wave = t >> 6, lane = t & 63;
  {
    float s = 0.f, sq = 0.f;
    #pragma unroll
    for (int l = 0; l < 4; ++l) {
      const float v = Zs[wave][lane + 64 * l];
      s += v;
      sq = fmaf(v, v, sq);
    }
    #pragma unroll
    for (int off = 32; off; off >>= 1) {
      s += __shfl_down(s, off);
      sq += __shfl_down(sq, off);
    }
    if (lane == 0) {
      const float m = s * (1.0f / 256.0f);
      const float var = sq * (1.0f / 256.0f) - m * m;
      mu_s[wave] = m;
      rs_s[wave] = rsqrtf(var + 1e-5f);
    }
  }
  __syncthreads();

  const float g = gamma[t], be = beta[t];
  #pragma unroll
  for (int kk = 0; kk < 4; ++kk)
    Z[(k0 + kk) * D256 + t] = (accM[kk] - mu_s[kk]) * rs_s[kk] * g + be;
}

// ---------------- k_B: T[k,i] = sum_j Z[k,j]*P[i,j]*cos(2pi*k/p_ij) ----------
// grid 256 (k-tiles of 8), 1024 threads = (j-quarter h) x (i).
// Chebyshev over the k-tile: c_{m+1} = cb2*c_m - c_{m-1}
__global__ __launch_bounds__(1024) void k_B(const float* __restrict__ Z,
                                            const float4* __restrict__ PIt4,
                                            float* __restrict__ T) {
  __shared__ float Zs[KT][D256];        // 8 KB
  __shared__ float red[4][KT][D256];    // 32 KB
  const int tid = threadIdx.x;
  const int i = tid & 255;
  const int h = tid >> 8;               // j-quarter (wave-uniform)
  const int k0 = blockIdx.x * KT;

  ((float*)Zs)[tid]        = Z[k0 * D256 + tid];
  ((float*)Zs)[tid + 1024] = Z[k0 * D256 + 1024 + tid];
  __syncthreads();

  float accT[KT] = {};
  const float kf0 = (float)k0, kf1 = (float)(k0 + 1);
  const int j0 = h * 64;
  for (int jj = 0; jj < 64; ++jj) {
    const int j = j0 + jj;
    const float4 pi = PIt4[j * D256 + i];
    float zv[KT];
    #pragma unroll
    for (int kk = 0; kk < KT; ++kk) zv[kk] = Zs[kk][j];   // wave-broadcast
    float r0 = kf0 * pi.y; r0 -= floorf(r0);
    float r1 = kf1 * pi.y; r1 -= floorf(r1);
    float c0 = __builtin_amdgcn_cosf(r0);
    float c1 = __builtin_amdgcn_cosf(r1);
    accT[0] = fmaf(zv[0] * pi.x, c0, accT[0]);
    accT[1] = fmaf(zv[1] * pi.x, c1, accT[1]);
    #pragma unroll
    for (int kk = 2; kk < KT; ++kk) {
      const float c2 = fmaf(pi.z, c1, -c0);
      accT[kk] = fmaf(zv[kk] * pi.x, c2, accT[kk]);
      c0 = c1;
      c1 = c2;
    }
  }

  #pragma unroll
  for (int kk = 0; kk < KT; ++kk) red[h][kk][i] = accT[kk];
  __syncthreads();

  // 1024 threads -> 2048 outputs (2 each)
  #pragma unroll
  for (int p = 0; p < 2; ++p) {
    const int kk = h + p * 4;
    const float s = red[0][kk][i] + red[1][kk][i] + red[2][kk][i] + red[3][kk][i];
    T[(k0 + kk) * D256 + i] = s;
  }
}

// ---------------- stage C1: split-s partial GEMM ----------------
__global__ __launch_bounds__(256) void k_C1(const float* __restrict__ T,
                                            const float* __restrict__ rfeat,
                                            const float* __restrict__ Linker,
                                            const float* __restrict__ rLinker,
                                            float* __restrict__ part) {
  __shared__ float Ls[128][8];
  __shared__ float rLs[128][8];
  const int bid = blockIdx.x;
  const int sc = bid & 7;
  const int tt = (bid >> 3) & 63;
  const int b  = bid >> 9;
  const int t0 = tt * 8;
  const int s0 = sc * 128;
  const int d  = threadIdx.x;

  {
    const int row = threadIdx.x >> 1;
    const int c4  = (threadIdx.x & 1) * 4;
    *(float4*)&Ls[row][c4]  = *(const float4*)&Linker[(s0 + row) * OUTSEQ + t0 + c4];
    *(float4*)&rLs[row][c4] = *(const float4*)&rLinker[(s0 + row) * OUTSEQ + t0 + c4];
  }
  __syncthreads();

  float acc[8] = {};
  const float* Tp = &T[(b * S_SEQ + s0) * D256 + d];
  const float* Rp = &rfeat[(b * S_SEQ + s0) * D256 + d];
  #pragma unroll 4
  for (int s = 0; s < 128; ++s) {
    const float tv = Tp[s * D256];
    const float rv = Rp[s * D256];
    const float4 l0 = *(const float4*)&Ls[s][0];
    const float4 l1 = *(const float4*)&Ls[s][4];
    const float4 r0 = *(const float4*)&rLs[s][0];
    const float4 r1 = *(const float4*)&rLs[s][4];
    acc[0] = fmaf(tv, l0.x, acc[0]); acc[0] = fmaf(rv, r0.x, acc[0]);
    acc[1] = fmaf(tv, l0.y, acc[1]); acc[1] = fmaf(rv, r0.y, acc[1]);
    acc[2] = fmaf(tv, l0.z, acc[2]); acc[2] = fmaf(rv, r0.z, acc[2]);
    acc[3] = fmaf(tv, l0.w, acc[3]); acc[3] = fmaf(rv, r0.w, acc[3]);
    acc[4] = fmaf(tv, l1.x, acc[4]); acc[4] = fmaf(rv, r1.x, acc[4]);
    acc[5] = fmaf(tv, l1.y, acc[5]); acc[5] = fmaf(rv, r1.y, acc[5]);
    acc[6] = fmaf(tv, l1.z, acc[6]); acc[6] = fmaf(rv, r1.z, acc[6]);
    acc[7] = fmaf(tv, l1.w, acc[7]); acc[7] = fmaf(rv, r1.w, acc[7]);
  }

  const int rowbase = b * 512 + t0;
  #pragma unroll
  for (int u = 0; u < 8; ++u)
    part[(((sc << 10) + rowbase + u) << 8) + d] = acc[u];
}

// ---------------- stage C2: reduce the 8 s-chunk partials ----------------
__global__ __launch_bounds__(256) void k_C2(const float* __restrict__ part,
                                            float* __restrict__ out) {
  const int row = blockIdx.x;   // 0..1023
  const int d   = threadIdx.x;
  float s = 0.f;
  #pragma unroll
  for (int sc = 0; sc < 8; ++sc)
    s += part[(((sc << 10) + row) << 8) + d];
  out[(row << 8) + d] = s;
}

extern "C" void kernel_launch(void* const* d_in, const int* in_sizes, int n_in,
                              void* d_out, int out_size, void* d_ws, size_t ws_size,
                              hipStream_t stream) {
  const float* x       = (const float*)d_in[0];
  const float* M       = (const float*)d_in[1];
  const float* P       = (const float*)d_in[2];
  const float* Linker  = (const float*)d_in[3];
  const float* gamma   = (const float*)d_in[4];
  const float* beta    = (const float*)d_in[5];
  const float* resW    = (const float*)d_in[6];
  const float* rLinker = (const float*)d_in[7];
  float* out = (float*)d_out;

  char* ws = (char*)d_ws;
  float2* MW    = (float2*)(ws);                        // 0.5 MB
  float4* PIt4  = (float4*)(ws + 512 * 1024);           // 1 MB
  float*  Zb    = (float*)(ws + 1536 * 1024);           // 2 MB
  float*  T     = (float*)(ws + 3584 * 1024);           // 2 MB
  float*  rfeat = (float*)(ws + 5632 * 1024);           // 2 MB
  float*  part  = (float*)(ws + 7680 * 1024);           // 8 MB

  hipLaunchKernelGGL(k_prep, dim3(256),  dim3(256),  0, stream, M, resW, P, MW, PIt4);
  hipLaunchKernelGGL(k_A,    dim3(512),  dim3(256),  0, stream, x, MW, gamma, beta, Zb, rfeat);
  hipLaunchKernelGGL(k_B,    dim3(256),  dim3(1024), 0, stream, Zb, PIt4, T);
  hipLaunchKernelGGL(k_C1,   dim3(1024), dim3(256),  0, stream, T, rfeat, Linker, rLinker, part);
  hipLaunchKernelGGL(k_C2,   dim3(1024), dim3(256),  0, stream, part, out);
}